// Round 15
// baseline (110.471 us; speedup 1.0000x reference)
//
#include <hip/hip_runtime.h>

// Locally-connected 2x2 conv, unshared weights.
// x: [256 planes, 512, 512] f32; weights: [511*511, 4]; bias: [511*511]
// out: [256, 511, 511]; out row 0 / col 0 are zero.
// neuron index = 511*w + h == flat in-plane output index.
//
// v15 = v14 (asm-pinned weights, nt stores; 106.6us) + STAGGERED plane sweep.
// x (268MB) nearly fits L3 (256MB), but a lockstep 0->255 plane sweep is
// cyclic-thrash: at call end the oldest lines are exactly the next replay's
// first reads. Stagger: block (q,b) starts its 32-plane loop at offset
// s = b*NQ/256 and wraps -> no synchronized eviction wave; at call end every
// plane is recent for SOME blocks => cross-replay L3 hits. Work identical.

typedef float f4u __attribute__((ext_vector_type(4), aligned(4)));
typedef float f2u __attribute__((ext_vector_type(2), aligned(4)));

constexpr int PLANE_OUT = 511 * 511;    // 261121
constexpr int PLANE_IN  = 512 * 512;    // 262144
constexpr int PSTRIDE   = 8;            // plane phases == XCD count

__global__ __launch_bounds__(256, 7)    // 72 VGPR budget; 28 waves/CU
void lc_conv2x2_v15(const float* __restrict__ x,
                    const float4* __restrict__ weights,
                    const float* __restrict__ bias,
                    float* __restrict__ out, int planes) {
    const int q = blockIdx.x;           // 0..7 plane phase == XCD
    const int b = blockIdx.y;           // 0..255
    const int t = threadIdx.x;

    const int NQ = (planes - q + PSTRIDE - 1) / PSTRIDE;    // plane iters
    const int s  = (b * NQ) >> 8;       // staggered start offset (0..NQ-1)

    if (b == 255) {                     // tail block: single output o = 261120
        if (t != 0) return;             // (w,h) = (510,510)
        const float4 wt = weights[PLANE_OUT - 1];
        const float  bv = bias[PLANE_OUT - 1];
        for (int i = 0; i < NQ; ++i) {
            int idx = s + i; if (idx >= NQ) idx -= NQ;
            const int p = q + PSTRIDE * idx;
            const float* xp = x + (size_t)p * PLANE_IN;
            float v = xp[509 * 512 + 509] * wt.x + xp[509 * 512 + 510] * wt.y
                    + xp[510 * 512 + 509] * wt.z + xp[510 * 512 + 510] * wt.w + bv;
            out[(size_t)p * PLANE_OUT + (PLANE_OUT - 1)] = v;
        }
        return;
    }

    const int o0 = (b << 10) | (t << 2);        // 0..261116, multiple of 4
    const int w  = o0 / 511;                    // hoisted magic-div
    const int h  = o0 - w * 511;

    // plane-invariant per-j predicates: crossing + force-zero (borders)
    bool cj[4], zj[4];
    #pragma unroll
    for (int j = 0; j < 4; ++j) {
        const int hr = h + j;
        cj[j] = (hr >= 511);                    // crosses into row w+1
        const int wj = w + (cj[j] ? 1 : 0);
        const int hj = hr - (cj[j] ? 511 : 0);
        zj[j] = (wj == 0) || (hj == 0);         // row-0 / col-0 border
    }

    // ---- weights/bias -> registers ONCE; asm pin forbids rematerialization
    const float4 q0 = weights[o0],     q1 = weights[o0 + 1];
    const float4 q2 = weights[o0 + 2], q3 = weights[o0 + 3];
    const f4u    bq = *(const f4u*)(bias + o0);
    float w0x = q0.x, w0y = q0.y, w0z = q0.z, w0w = q0.w;
    float w1x = q1.x, w1y = q1.y, w1z = q1.z, w1w = q1.w;
    float w2x = q2.x, w2y = q2.y, w2z = q2.z, w2w = q2.w;
    float w3x = q3.x, w3y = q3.y, w3z = q3.z, w3w = q3.w;
    float b0 = bq.x, b1 = bq.y, b2 = bq.z, b3 = bq.w;
    asm volatile(""
        : "+v"(w0x), "+v"(w0y), "+v"(w0z), "+v"(w0w),
          "+v"(w1x), "+v"(w1y), "+v"(w1z), "+v"(w1w),
          "+v"(w2x), "+v"(w2y), "+v"(w2z), "+v"(w2w),
          "+v"(w3x), "+v"(w3y), "+v"(w3z), "+v"(w3w),
          "+v"(b0), "+v"(b1), "+v"(b2), "+v"(b3));
    const float wX[4] = {w0x, w1x, w2x, w3x};
    const float wY[4] = {w0y, w1y, w2y, w3y};
    const float wZ[4] = {w0z, w1z, w2z, w3z};
    const float wW[4] = {w0w, w1w, w2w, w3w};
    const float bR[4] = {b0, b1, b2, b3};

    // x bases: top-left of output o0 = flat(w-1, h-1) = o0 + w - 513
    int tb = o0 + w - 513;
    if (tb < 0) tb = 0;                         // w==0 rows are forced zero anyway
    const int bb = tb + 512;

    #pragma unroll 4
    for (int i = 0; i < NQ; ++i) {
        int idx = s + i; if (idx >= NQ) idx -= NQ;      // staggered wrap
        const int p = q + PSTRIDE * idx;
        const float* xp = x + (size_t)p * PLANE_IN;

        f4u T0 = *(const f4u*)(xp + tb);        // top row: 6 floats
        f2u T1 = *(const f2u*)(xp + tb + 4);
        f4u B0 = *(const f4u*)(xp + bb);        // bottom row: 6 floats
        f2u B1 = *(const f2u*)(xp + bb + 4);
        const float tv[6] = {T0.x, T0.y, T0.z, T0.w, T1.x, T1.y};
        const float bv[6] = {B0.x, B0.y, B0.z, B0.w, B1.x, B1.y};

        f4u r;
        #pragma unroll
        for (int j = 0; j < 4; ++j) {           // static indices; cj -> cndmask
            const float xtl = cj[j] ? tv[j + 1] : tv[j];
            const float xtr = cj[j] ? tv[j + 2] : tv[j + 1];
            const float xbl = cj[j] ? bv[j + 1] : bv[j];
            const float xbr = cj[j] ? bv[j + 2] : bv[j + 1];
            const float v = xtl * wX[j] + xtr * wY[j]
                          + xbl * wZ[j] + xbr * wW[j] + bR[j];
            r[j] = zj[j] ? 0.0f : v;
        }
        // full-line nontemporal store: out never allocates in L2/L3
        __builtin_nontemporal_store(r, (f4u*)(out + (size_t)p * PLANE_OUT + o0));
    }
}

extern "C" void kernel_launch(void* const* d_in, const int* in_sizes, int n_in,
                              void* d_out, int out_size, void* d_ws, size_t ws_size,
                              hipStream_t stream) {
    const float*  x       = (const float*)d_in[0];
    const float4* weights = (const float4*)d_in[1];
    const float*  bias    = (const float*)d_in[2];
    float*        out     = (float*)d_out;

    int planes = in_sizes[0] / PLANE_IN;        // 256
    dim3 grid(PSTRIDE, 256);                    // XCD = blockIdx.x under %8
    lc_conv2x2_v15<<<grid, 256, 0, stream>>>(x, weights, bias, out, planes);
}

// Round 16
// 101.242 us; speedup vs baseline: 1.0912x; 1.0912x over previous
//
#include <hip/hip_runtime.h>

// Locally-connected 2x2 conv, unshared weights.
// x: [256 planes, 512, 512] f32; weights: [511*511, 4]; bias: [511*511]
// out: [256, 511, 511]; out row 0 / col 0 are zero.
// neuron index = 511*w + h == flat in-plane output index.
//
// v16 = v14 (asm-pinned weights, nt stores; 106.6us best) with CONTIGUOUS
// per-phase plane chunks: phase q sweeps planes [q*32, q*32+32) instead of
// q, q+8, ... (stagger reverted -- R15 falsified the L3-thrash theory).
// Spreads the device's instantaneous DRAM footprint across 8 independent
// 32MB regions (one per XCD) instead of one shared 8-plane window, while
// keeping per-plane XCD ownership (L2 dedupe) and linear sweeps intact.

typedef float f4u __attribute__((ext_vector_type(4), aligned(4)));
typedef float f2u __attribute__((ext_vector_type(2), aligned(4)));

constexpr int PLANE_OUT = 511 * 511;    // 261121
constexpr int PLANE_IN  = 512 * 512;    // 262144
constexpr int PSTRIDE   = 8;            // plane phases == XCD count

__global__ __launch_bounds__(256, 7)    // 72 VGPR budget; 28 waves/CU
void lc_conv2x2_v16(const float* __restrict__ x,
                    const float4* __restrict__ weights,
                    const float* __restrict__ bias,
                    float* __restrict__ out, int planes) {
    const int q = blockIdx.x;           // 0..7 plane phase == XCD
    const int b = blockIdx.y;           // 0..255
    const int t = threadIdx.x;

    const int NQ = planes >> 3;         // 32 planes per phase
    const int p0 = q * NQ;              // contiguous chunk [p0, p0+NQ)

    if (b == 255) {                     // tail block: single output o = 261120
        if (t != 0) return;             // (w,h) = (510,510)
        const float4 wt = weights[PLANE_OUT - 1];
        const float  bv = bias[PLANE_OUT - 1];
        for (int i = 0; i < NQ; ++i) {
            const int p = p0 + i;
            const float* xp = x + (size_t)p * PLANE_IN;
            float v = xp[509 * 512 + 509] * wt.x + xp[509 * 512 + 510] * wt.y
                    + xp[510 * 512 + 509] * wt.z + xp[510 * 512 + 510] * wt.w + bv;
            out[(size_t)p * PLANE_OUT + (PLANE_OUT - 1)] = v;
        }
        return;
    }

    const int o0 = (b << 10) | (t << 2);        // 0..261116, multiple of 4
    const int w  = o0 / 511;                    // hoisted magic-div
    const int h  = o0 - w * 511;

    // plane-invariant per-j predicates: crossing + force-zero (borders)
    bool cj[4], zj[4];
    #pragma unroll
    for (int j = 0; j < 4; ++j) {
        const int hr = h + j;
        cj[j] = (hr >= 511);                    // crosses into row w+1
        const int wj = w + (cj[j] ? 1 : 0);
        const int hj = hr - (cj[j] ? 511 : 0);
        zj[j] = (wj == 0) || (hj == 0);         // row-0 / col-0 border
    }

    // ---- weights/bias -> registers ONCE; asm pin forbids rematerialization
    const float4 q0 = weights[o0],     q1 = weights[o0 + 1];
    const float4 q2 = weights[o0 + 2], q3 = weights[o0 + 3];
    const f4u    bq = *(const f4u*)(bias + o0);
    float w0x = q0.x, w0y = q0.y, w0z = q0.z, w0w = q0.w;
    float w1x = q1.x, w1y = q1.y, w1z = q1.z, w1w = q1.w;
    float w2x = q2.x, w2y = q2.y, w2z = q2.z, w2w = q2.w;
    float w3x = q3.x, w3y = q3.y, w3z = q3.z, w3w = q3.w;
    float b0 = bq.x, b1 = bq.y, b2 = bq.z, b3 = bq.w;
    asm volatile(""
        : "+v"(w0x), "+v"(w0y), "+v"(w0z), "+v"(w0w),
          "+v"(w1x), "+v"(w1y), "+v"(w1z), "+v"(w1w),
          "+v"(w2x), "+v"(w2y), "+v"(w2z), "+v"(w2w),
          "+v"(w3x), "+v"(w3y), "+v"(w3z), "+v"(w3w),
          "+v"(b0), "+v"(b1), "+v"(b2), "+v"(b3));
    const float wX[4] = {w0x, w1x, w2x, w3x};
    const float wY[4] = {w0y, w1y, w2y, w3y};
    const float wZ[4] = {w0z, w1z, w2z, w3z};
    const float wW[4] = {w0w, w1w, w2w, w3w};
    const float bR[4] = {b0, b1, b2, b3};

    // x bases: top-left of output o0 = flat(w-1, h-1) = o0 + w - 513
    int tb = o0 + w - 513;
    if (tb < 0) tb = 0;                         // w==0 rows are forced zero anyway
    const int bb = tb + 512;

    #pragma unroll 4
    for (int i = 0; i < NQ; ++i) {
        const int p = p0 + i;                   // contiguous per-XCD sweep
        const float* xp = x + (size_t)p * PLANE_IN;

        f4u T0 = *(const f4u*)(xp + tb);        // top row: 6 floats
        f2u T1 = *(const f2u*)(xp + tb + 4);
        f4u B0 = *(const f4u*)(xp + bb);        // bottom row: 6 floats
        f2u B1 = *(const f2u*)(xp + bb + 4);
        const float tv[6] = {T0.x, T0.y, T0.z, T0.w, T1.x, T1.y};
        const float bv[6] = {B0.x, B0.y, B0.z, B0.w, B1.x, B1.y};

        f4u r;
        #pragma unroll
        for (int j = 0; j < 4; ++j) {           // static indices; cj -> cndmask
            const float xtl = cj[j] ? tv[j + 1] : tv[j];
            const float xtr = cj[j] ? tv[j + 2] : tv[j + 1];
            const float xbl = cj[j] ? bv[j + 1] : bv[j];
            const float xbr = cj[j] ? bv[j + 2] : bv[j + 1];
            const float v = xtl * wX[j] + xtr * wY[j]
                          + xbl * wZ[j] + xbr * wW[j] + bR[j];
            r[j] = zj[j] ? 0.0f : v;
        }
        // full-line nontemporal store: out never allocates in L2/L3
        __builtin_nontemporal_store(r, (f4u*)(out + (size_t)p * PLANE_OUT + o0));
    }
}

extern "C" void kernel_launch(void* const* d_in, const int* in_sizes, int n_in,
                              void* d_out, int out_size, void* d_ws, size_t ws_size,
                              hipStream_t stream) {
    const float*  x       = (const float*)d_in[0];
    const float4* weights = (const float4*)d_in[1];
    const float*  bias    = (const float*)d_in[2];
    float*        out     = (float*)d_out;

    int planes = in_sizes[0] / PLANE_IN;        // 256
    dim3 grid(PSTRIDE, 256);                    // XCD = blockIdx.x under %8
    lc_conv2x2_v16<<<grid, 256, 0, stream>>>(x, weights, bias, out, planes);
}